// Round 1
// 236.665 us; speedup vs baseline: 1.0112x; 1.0112x over previous
//
#include <hip/hip_runtime.h>
#include <hip/hip_fp16.h>

// Problem constants (fixed by setup_inputs)
#define BB   2
#define CCH  256
#define HH   200
#define WW   336
#define HWN  (HH * WW)
#define OH   7
#define OW   7
#define SCALEF 0.25f
#define NBIN (OH * OW)          // 49
#define PER_ROI (CCH * NBIN)    // 12544 floats per roi
#define NBANDS 8
#define NBUCK (BB * NBANDS)
#define CHALF 128               // channels per roi-block (channel split)
#define HALF_OUT (CHALF * NBIN) // 6272 floats = 392 full 64B lines

// native vector type: __builtin_nontemporal_* requires real vectors, not
// HIP_vector_type classes
typedef float  nfloat4 __attribute__((ext_vector_type(4)));

__device__ __forceinline__ __half2 u32_as_h2(unsigned int u) {
    union { unsigned int u; __half2 h; } c;
    c.u = u;
    return c.h;
}

// ---------------------------------------------------------------------------
// Kernel 1: transpose+convert (B, C, H, W) fp32 -> (B, H*W, C) fp16.
// 64x64 tiles; float4 nontemporal reads; ushort4 coalesced writes.
// Block (0,0,0) also buckets rois by (batch, y-band) into perm[] (runs
// concurrent with the other tiles; saves a serialized launch).
// ---------------------------------------------------------------------------
__global__ __launch_bounds__(256) void transpose_f16_k(const float* __restrict__ src,
                                                       unsigned short* __restrict__ dst,
                                                       const float* __restrict__ rois,
                                                       int N, int* __restrict__ perm) {
    __shared__ float tile[64][65];
    __shared__ int cnt[NBUCK], off[NBUCK];
    __shared__ unsigned char keys[1024];

    const int tx  = threadIdx.x;   // 0..15
    const int ty  = threadIdx.y;   // 0..15
    const int tid = ty * 16 + tx;  // 0..255

    if (blockIdx.x == 0 && blockIdx.y == 0 && blockIdx.z == 0) {
        if (N > 1024 || N < 8) {
            for (int i = tid; i < N; i += 256) perm[i] = i;
        } else {
            if (tid < NBUCK) cnt[tid] = 0;
            __syncthreads();
            for (int i = tid; i < N; i += 256) {
                const float* r = rois + i * 5;
                const int b = (int)r[0];
                const float yc = (r[2] + r[4]) * 0.5f * SCALEF;
                int band = (int)(yc * ((float)NBANDS / (float)HH));
                band = min(max(band, 0), NBANDS - 1);
                const int k = b * NBANDS + band;
                keys[i] = (unsigned char)k;
                atomicAdd(&cnt[k], 1);
            }
            __syncthreads();
            if (tid == 0) {
                int s = 0;
                for (int k = 0; k < NBUCK; ++k) { off[k] = s; s += cnt[k]; }
            }
            __syncthreads();
            for (int i = tid; i < N; i += 256) {
                perm[atomicAdd(&off[keys[i]], 1)] = i;
            }
        }
        __syncthreads();
    }

    const int b   = blockIdx.z;
    const int hw0 = blockIdx.x * 64;
    const int c0  = blockIdx.y * 64;

#pragma unroll
    for (int r = 0; r < 4; ++r) {
        const int cl = ty + r * 16;                                 // 0..63
        const nfloat4 v = __builtin_nontemporal_load(
            (const nfloat4*)(src + (size_t)(b * CCH + c0 + cl) * HWN + hw0 + tx * 4));
        tile[cl][tx * 4 + 0] = v.x;
        tile[cl][tx * 4 + 1] = v.y;
        tile[cl][tx * 4 + 2] = v.z;
        tile[cl][tx * 4 + 3] = v.w;
    }
    __syncthreads();
#pragma unroll
    for (int r = 0; r < 4; ++r) {
        const int hwl = ty + r * 16;                                // 0..63
        ushort4 o;
        o.x = __half_as_ushort(__float2half(tile[tx * 4 + 0][hwl]));  // RNE
        o.y = __half_as_ushort(__float2half(tile[tx * 4 + 1][hwl]));
        o.z = __half_as_ushort(__float2half(tile[tx * 4 + 2][hwl]));
        o.w = __half_as_ushort(__float2half(tile[tx * 4 + 3][hwl]));
        *(ushort4*)(dst + (size_t)(b * HWN + hw0 + hwl) * CCH + c0 + tx * 4) = o;
    }
}

// ---------------------------------------------------------------------------
// Kernel 2: RoIAlign, quarter-tap structure, channel-split.
// Grid (N, 2): blockIdx.y picks 128 of 256 channels. Wave = 16 lanes x 8 ch
// (uint4) covering 128 ch, x 4 quarters = the 4 bilinear taps (q&1 = x-tap,
// q>>1 = y-tap). ONE dwordx4 per sample fetches all 4 taps for 128 ch; the
// bilinear sum = per-quarter scalar weight x tap, reduced with two shfl_xor
// (16, 32) per BIN.
//
// This revision (issue-bound, not BW-bound — features are L2/L3-resident):
//  - quarter-indexed tables s_{yb,xb}[2][14] + folded weights s_{wy,wx}[2][14]
//    (validity mask and the 0.25 mean factor pre-multiplied): one ds_read
//    replaces {2 ds_reads + cndmask + muls} per tap side.
//  - fp32 LDS staging (25 KB; still 4 blocks/CU at 8 waves/SIMD): removes
//    8 float->half cvts per bin and all drain cvts, and removes the output's
//    second fp16 rounding (absmax margin improves).
//  - staging writes predicated to quarter 0 (lane<16): kills the 4-way
//    same-address ds_write conflict and 3/4 of the write issue slots.
// ---------------------------------------------------------------------------
__global__ __launch_bounds__(512, 8) void roi_align_f16_k(const unsigned short* __restrict__ f,
                                                          const float* __restrict__ rois,
                                                          const int* __restrict__ perm,
                                                          float* __restrict__ out) {
    const int nblk = gridDim.x;
    int p;
    if ((nblk & 7) == 0) {
        p = (blockIdx.x & 7) * (nblk >> 3) + (blockIdx.x >> 3);  // XCD y-band swizzle
    } else {
        p = blockIdx.x;
    }
    const int n    = perm[p];
    const int cb   = blockIdx.y;     // channel half: 0 or 1
    const int tid  = threadIdx.x;
    const int lane = tid & 63;
    const int l16  = lane & 15;      // channel group within half
    const int qx   = (lane >> 4) & 1;  // quarter: x-tap select
    const int qy   = lane >> 5;        // quarter: y-tap select
    const int g    = tid >> 6;       // 0..7 bin-group
    const int c8   = l16 * 8;        // 8 local channels per lane

    __shared__ __align__(16) float buf_f[HALF_OUT];   // 25,088 B fp32 staging
    __shared__ int   s_yb[2][14];    // [y-tap][sample row] feature base offset
    __shared__ int   s_xb[2][14];    // [x-tap][sample col] feature col offset
    __shared__ float s_wy[2][14];    // folded: (tap lerp) * vy * 0.5
    __shared__ float s_wx[2][14];    // folded: (tap lerp) * vx * 0.5

    const float* r = rois + n * 5;
    const int   b   = (int)r[0];
    const float rx1 = r[1] * SCALEF, ry1 = r[2] * SCALEF;
    const float rx2 = r[3] * SCALEF, ry2 = r[4] * SCALEF;
    const float bw = fmaxf(rx2 - rx1, 1.0f) * (1.0f / OW);
    const float bh = fmaxf(ry2 - ry1, 1.0f) * (1.0f / OH);

    if (tid < 14) {
        const float ys = ry1 + ((float)tid + 0.5f) * (bh * 0.5f);
        const float vy = (ys >= -1.0f && ys <= (float)HH) ? 0.5f : 0.0f;  // mask*0.5
        const float y = fminf(fmaxf(ys, 0.0f), (float)(HH - 1));
        const int y0  = (int)floorf(y);
        const int y1  = min(y0 + 1, HH - 1);
        const float ly = y - (float)y0;
        s_yb[0][tid] = (b * HH + y0) * (WW * CCH);
        s_yb[1][tid] = (b * HH + y1) * (WW * CCH);
        s_wy[0][tid] = (1.0f - ly) * vy;
        s_wy[1][tid] = ly * vy;
    } else if (tid >= 64 && tid < 78) {
        const int j = tid - 64;
        const float xs = rx1 + ((float)j + 0.5f) * (bw * 0.5f);
        const float vx = (xs >= -1.0f && xs <= (float)WW) ? 0.5f : 0.0f;  // mask*0.5
        const float x = fminf(fmaxf(xs, 0.0f), (float)(WW - 1));
        const int x0  = (int)floorf(x);
        const int x1  = min(x0 + 1, WW - 1);
        const float lx = x - (float)x0;
        s_xb[0][j] = x0 * CCH;
        s_xb[1][j] = x1 * CCH;
        s_wx[0][j] = (1.0f - lx) * vx;
        s_wx[1][j] = lx * vx;
    }
    __syncthreads();

    const unsigned short* fp = f + cb * CHALF + c8;

    for (int bin = g; bin < NBIN; bin += 8) {
        const int ph = bin / OW;
        const int pw = bin - ph * OW;
        float acc[8] = {0.f, 0.f, 0.f, 0.f, 0.f, 0.f, 0.f, 0.f};
#pragma unroll
        for (int iy = 0; iy < 2; ++iy) {
            const int py   = ph * 2 + iy;
            const int ybs  = s_yb[qy][py];     // my quarter's y-tap base
            const float wy = s_wy[qy][py];     // mask+mean-folded y weight
#pragma unroll
            for (int ix = 0; ix < 2; ++ix) {
                const int px  = pw * 2 + ix;
                const float w = wy * s_wx[qx][px];
                // ONE load: all 4 taps of this sample, 128 ch wave-wide
                const uint4 q = *(const uint4*)(fp + ybs + s_xb[qx][px]);
                const float2 f0 = __half22float2(u32_as_h2(q.x));
                const float2 f1 = __half22float2(u32_as_h2(q.y));
                const float2 f2 = __half22float2(u32_as_h2(q.z));
                const float2 f3 = __half22float2(u32_as_h2(q.w));
                acc[0] += w * f0.x;  acc[1] += w * f0.y;
                acc[2] += w * f1.x;  acc[3] += w * f1.y;
                acc[4] += w * f2.x;  acc[5] += w * f2.y;
                acc[6] += w * f3.x;  acc[7] += w * f3.y;
            }
        }
        // reduce the 4 quarters: x-taps (lane^16), then y-taps (lane^32)
#pragma unroll
        for (int j = 0; j < 8; ++j) {
            acc[j] += __shfl_xor(acc[j], 16);
            acc[j] += __shfl_xor(acc[j], 32);
        }
        // quarter 0 only: no 4-way same-address conflict, 1/4 the ds_writes
        if (lane < 16) {
#pragma unroll
            for (int j = 0; j < 8; ++j) {
                buf_f[(c8 + j) * NBIN + bin] = acc[j];
            }
        }
    }
    __syncthreads();

    // Drain: buf_f is this half's linear (128,7,7) fp32 order; region is
    // exactly 392 full 64B lines -> clean coalesced nontemporal float4 stores,
    // no conversion needed.
    nfloat4* ob = (nfloat4*)(out + (size_t)n * PER_ROI + cb * HALF_OUT);
    const nfloat4* bb = (const nfloat4*)buf_f;
    for (int i = tid; i < HALF_OUT / 4; i += 512) {
        __builtin_nontemporal_store(bb[i], ob + i);
    }
}

// ---------------------------------------------------------------------------
// Fallback (workspace too small): original-layout fp32, correct but slow.
// ---------------------------------------------------------------------------
__global__ __launch_bounds__(256) void roi_align_direct_k(const float* __restrict__ f,
                                                          const float* __restrict__ rois,
                                                          float* __restrict__ out) {
    const int n   = blockIdx.x;
    const int c   = threadIdx.x;

    __shared__ int   s_y0[14], s_y1[14], s_x0[14], s_x1[14];
    __shared__ float s_ly[14], s_lx[14], s_vy[14], s_vx[14];

    const float* r = rois + n * 5;
    const int   b   = (int)r[0];
    const float rx1 = r[1] * SCALEF, ry1 = r[2] * SCALEF;
    const float rx2 = r[3] * SCALEF, ry2 = r[4] * SCALEF;
    const float bw = fmaxf(rx2 - rx1, 1.0f) * (1.0f / OW);
    const float bh = fmaxf(ry2 - ry1, 1.0f) * (1.0f / OH);

    if (c < 14) {
        const float ys = ry1 + ((float)c + 0.5f) * (bh * 0.5f);
        s_vy[c] = (ys >= -1.0f && ys <= (float)HH) ? 1.0f : 0.0f;
        const float y = fminf(fmaxf(ys, 0.0f), (float)(HH - 1));
        const int y0  = (int)floorf(y);
        s_y0[c] = y0 * WW;
        s_y1[c] = min(y0 + 1, HH - 1) * WW;
        s_ly[c] = y - (float)y0;
    } else if (c >= 64 && c < 78) {
        const int j = c - 64;
        const float xs = rx1 + ((float)j + 0.5f) * (bw * 0.5f);
        s_vx[j] = (xs >= -1.0f && xs <= (float)WW) ? 1.0f : 0.0f;
        const float x = fminf(fmaxf(xs, 0.0f), (float)(WW - 1));
        const int x0  = (int)floorf(x);
        s_x0[j] = x0;
        s_x1[j] = min(x0 + 1, WW - 1);
        s_lx[j] = x - (float)x0;
    }
    __syncthreads();

    const float* fb = f + (size_t)(b * CCH + c) * HWN;
    for (int bin = 0; bin < NBIN; ++bin) {
        const int ph = bin / OW, pw = bin - ph * OW;
        float acc = 0.0f;
        for (int iy = 0; iy < 2; ++iy) {
            const int py = ph * 2 + iy;
            const float ly = s_ly[py], hy = 1.0f - ly;
            for (int ix = 0; ix < 2; ++ix) {
                const int px = pw * 2 + ix;
                const float lx = s_lx[px], hx = 1.0f - lx;
                const float m = s_vy[py] * s_vx[px] * 0.25f;
                acc += m * (hy * (hx * fb[s_y0[py] + s_x0[px]] + lx * fb[s_y0[py] + s_x1[px]]) +
                            ly * (hx * fb[s_y1[py] + s_x0[px]] + lx * fb[s_y1[py] + s_x1[px]]));
            }
        }
        out[(size_t)n * PER_ROI + c * NBIN + bin] = acc;
    }
}

extern "C" void kernel_launch(void* const* d_in, const int* in_sizes, int n_in,
                              void* d_out, int out_size, void* d_ws, size_t ws_size,
                              hipStream_t stream) {
    const float* feat = (const float*)d_in[0];
    const float* rois = (const float*)d_in[1];
    float* out = (float*)d_out;
    const int N = in_sizes[1] / 5;

    const size_t tensor_bytes = (size_t)BB * CCH * HWN * sizeof(unsigned short); // 68.8 MB
    const size_t need = tensor_bytes + (size_t)N * sizeof(int);
    if (ws_size >= need) {
        unsigned short* fcl = (unsigned short*)d_ws;
        int* perm = (int*)((char*)d_ws + tensor_bytes);   // tensor_bytes is 256-aligned
        transpose_f16_k<<<dim3(HWN / 64, CCH / 64, BB), dim3(16, 16), 0, stream>>>(
            feat, fcl, rois, N, perm);
        roi_align_f16_k<<<dim3(N, 2), 512, 0, stream>>>(fcl, rois, perm, out);
    } else {
        roi_align_direct_k<<<N, 256, 0, stream>>>(feat, rois, out);
    }
}

// Round 2
// 235.202 us; speedup vs baseline: 1.0175x; 1.0062x over previous
//
#include <hip/hip_runtime.h>
#include <hip/hip_fp16.h>

// Problem constants (fixed by setup_inputs)
#define BB   2
#define CCH  256
#define HH   200
#define WW   336
#define HWN  (HH * WW)
#define OH   7
#define OW   7
#define SCALEF 0.25f
#define NBIN (OH * OW)          // 49
#define PER_ROI (CCH * NBIN)    // 12544 floats per roi
#define NBANDS 8
#define NBUCK (BB * NBANDS)
#define CHALF 128               // channels per roi-block (channel split)
#define HALF_OUT (CHALF * NBIN) // 6272 floats = 392 full 64B lines

// native vector types: __builtin_nontemporal_* requires real vectors, not
// HIP_vector_type classes
typedef float  nfloat4 __attribute__((ext_vector_type(4)));
typedef unsigned short ushort8v __attribute__((ext_vector_type(8)));

__device__ __forceinline__ __half2 u32_as_h2(unsigned int u) {
    union { unsigned int u; __half2 h; } c;
    c.u = u;
    return c.h;
}

// ---------------------------------------------------------------------------
// Kernel 1: transpose+convert (B, C, H, W) fp32 -> (B, H*W, C) fp16.
// v2: fp16-in-LDS with granule XOR swizzle.
//  - 64 hw x 128 c tiles (c-tile doubled): global stores are dwordx4 with
//    256B-contiguous rows (was dwordx2 / 128B).
//  - LDS layout [hw][128 c] fp16, 16 KB, NO pad; 16B granule g=c>>3 stored
//    at g^(hw>>2). Keeps every b128 access 16B-aligned while spreading the
//    write-phase banks (~4-way on 2B writes, free 2-way on b128 reads).
//  - read-out phase: 4 x ds_read_b128 per thread (was 16 x ds_read_b32).
// Block (0,0,0) also buckets rois by (batch, y-band) into perm[] (runs
// concurrent with the other tiles; saves a serialized launch).
// ---------------------------------------------------------------------------
__global__ __launch_bounds__(256) void transpose_f16_k(const float* __restrict__ src,
                                                       unsigned short* __restrict__ dst,
                                                       const float* __restrict__ rois,
                                                       int N, int* __restrict__ perm) {
    __shared__ unsigned short t16[64 * 128];   // 16,384 B
    __shared__ int cnt[NBUCK], off[NBUCK];
    __shared__ unsigned char keys[1024];

    const int tx  = threadIdx.x;   // 0..15
    const int ty  = threadIdx.y;   // 0..15
    const int tid = ty * 16 + tx;  // 0..255

    if (blockIdx.x == 0 && blockIdx.y == 0 && blockIdx.z == 0) {
        if (N > 1024 || N < 8) {
            for (int i = tid; i < N; i += 256) perm[i] = i;
        } else {
            if (tid < NBUCK) cnt[tid] = 0;
            __syncthreads();
            for (int i = tid; i < N; i += 256) {
                const float* r = rois + i * 5;
                const int b = (int)r[0];
                const float yc = (r[2] + r[4]) * 0.5f * SCALEF;
                int band = (int)(yc * ((float)NBANDS / (float)HH));
                band = min(max(band, 0), NBANDS - 1);
                const int k = b * NBANDS + band;
                keys[i] = (unsigned char)k;
                atomicAdd(&cnt[k], 1);
            }
            __syncthreads();
            if (tid == 0) {
                int s = 0;
                for (int k = 0; k < NBUCK; ++k) { off[k] = s; s += cnt[k]; }
            }
            __syncthreads();
            for (int i = tid; i < N; i += 256) {
                perm[atomicAdd(&off[keys[i]], 1)] = i;
            }
        }
        __syncthreads();
    }

    const int b   = blockIdx.z;
    const int hw0 = blockIdx.x * 64;
    const int c0  = blockIdx.y * 128;

    // Read: thread (tx,ty) iter r covers channel cl = ty + r*16, hw = tx*4..+3.
    // Swizzled column index: granule (cl>>3) ^ tx  (tx == hw>>2 for all 4 hw).
#pragma unroll
    for (int r = 0; r < 8; ++r) {
        const int cl = ty + r * 16;                                 // 0..127
        const nfloat4 v = __builtin_nontemporal_load(
            (const nfloat4*)(src + (size_t)(b * CCH + c0 + cl) * HWN + hw0 + tx * 4));
        const int cz = (((cl >> 3) ^ tx) << 3) + (cl & 7);          // swizzled col
        t16[(tx * 4 + 0) * 128 + cz] = __half_as_ushort(__float2half(v.x));  // RNE
        t16[(tx * 4 + 1) * 128 + cz] = __half_as_ushort(__float2half(v.y));
        t16[(tx * 4 + 2) * 128 + cz] = __half_as_ushort(__float2half(v.z));
        t16[(tx * 4 + 3) * 128 + cz] = __half_as_ushort(__float2half(v.w));
    }
    __syncthreads();

    // Write: lane handles (hwl, cg): one ds_read_b128 from swizzled granule,
    // one dwordx4 store; 16 lanes x 16B = 256B contiguous per hw row.
    const int cg = tid & 15;
#pragma unroll
    for (int wv = 0; wv < 4; ++wv) {
        const int hwl = (tid >> 4) + wv * 16;                       // 0..63
        const ushort8v o = *(const ushort8v*)&t16[hwl * 128 + ((cg ^ (hwl >> 2)) << 3)];
        *(ushort8v*)(dst + (size_t)(b * HWN + hw0 + hwl) * CCH + c0 + cg * 8) = o;
    }
}

// ---------------------------------------------------------------------------
// Kernel 2: RoIAlign, quarter-tap structure, channel-split. (unchanged this
// round for clean attribution of the transpose rewrite)
// Grid (N, 2): blockIdx.y picks 128 of 256 channels. Wave = 16 lanes x 8 ch
// (uint4) covering 128 ch, x 4 quarters = the 4 bilinear taps (q&1 = x-tap,
// q>>1 = y-tap). ONE dwordx4 per sample fetches all 4 taps for 128 ch; the
// bilinear sum = per-quarter scalar weight x tap (clang fuses cvt+fma into
// v_fma_mix_f32), reduced with two shfl_xor (16, 32) per BIN. fp32 LDS
// staging; quarter-0-only staging writes; folded weight tables.
// ---------------------------------------------------------------------------
__global__ __launch_bounds__(512, 8) void roi_align_f16_k(const unsigned short* __restrict__ f,
                                                          const float* __restrict__ rois,
                                                          const int* __restrict__ perm,
                                                          float* __restrict__ out) {
    const int nblk = gridDim.x;
    int p;
    if ((nblk & 7) == 0) {
        p = (blockIdx.x & 7) * (nblk >> 3) + (blockIdx.x >> 3);  // XCD y-band swizzle
    } else {
        p = blockIdx.x;
    }
    const int n    = perm[p];
    const int cb   = blockIdx.y;     // channel half: 0 or 1
    const int tid  = threadIdx.x;
    const int lane = tid & 63;
    const int l16  = lane & 15;      // channel group within half
    const int qx   = (lane >> 4) & 1;  // quarter: x-tap select
    const int qy   = lane >> 5;        // quarter: y-tap select
    const int g    = tid >> 6;       // 0..7 bin-group
    const int c8   = l16 * 8;        // 8 local channels per lane

    __shared__ __align__(16) float buf_f[HALF_OUT];   // 25,088 B fp32 staging
    __shared__ int   s_yb[2][14];    // [y-tap][sample row] feature base offset
    __shared__ int   s_xb[2][14];    // [x-tap][sample col] feature col offset
    __shared__ float s_wy[2][14];    // folded: (tap lerp) * vy * 0.5
    __shared__ float s_wx[2][14];    // folded: (tap lerp) * vx * 0.5

    const float* r = rois + n * 5;
    const int   b   = (int)r[0];
    const float rx1 = r[1] * SCALEF, ry1 = r[2] * SCALEF;
    const float rx2 = r[3] * SCALEF, ry2 = r[4] * SCALEF;
    const float bw = fmaxf(rx2 - rx1, 1.0f) * (1.0f / OW);
    const float bh = fmaxf(ry2 - ry1, 1.0f) * (1.0f / OH);

    if (tid < 14) {
        const float ys = ry1 + ((float)tid + 0.5f) * (bh * 0.5f);
        const float vy = (ys >= -1.0f && ys <= (float)HH) ? 0.5f : 0.0f;  // mask*0.5
        const float y = fminf(fmaxf(ys, 0.0f), (float)(HH - 1));
        const int y0  = (int)floorf(y);
        const int y1  = min(y0 + 1, HH - 1);
        const float ly = y - (float)y0;
        s_yb[0][tid] = (b * HH + y0) * (WW * CCH);
        s_yb[1][tid] = (b * HH + y1) * (WW * CCH);
        s_wy[0][tid] = (1.0f - ly) * vy;
        s_wy[1][tid] = ly * vy;
    } else if (tid >= 64 && tid < 78) {
        const int j = tid - 64;
        const float xs = rx1 + ((float)j + 0.5f) * (bw * 0.5f);
        const float vx = (xs >= -1.0f && xs <= (float)WW) ? 0.5f : 0.0f;  // mask*0.5
        const float x = fminf(fmaxf(xs, 0.0f), (float)(WW - 1));
        const int x0  = (int)floorf(x);
        const int x1  = min(x0 + 1, WW - 1);
        const float lx = x - (float)x0;
        s_xb[0][j] = x0 * CCH;
        s_xb[1][j] = x1 * CCH;
        s_wx[0][j] = (1.0f - lx) * vx;
        s_wx[1][j] = lx * vx;
    }
    __syncthreads();

    const unsigned short* fp = f + cb * CHALF + c8;

    for (int bin = g; bin < NBIN; bin += 8) {
        const int ph = bin / OW;
        const int pw = bin - ph * OW;
        float acc[8] = {0.f, 0.f, 0.f, 0.f, 0.f, 0.f, 0.f, 0.f};
#pragma unroll
        for (int iy = 0; iy < 2; ++iy) {
            const int py   = ph * 2 + iy;
            const int ybs  = s_yb[qy][py];     // my quarter's y-tap base
            const float wy = s_wy[qy][py];     // mask+mean-folded y weight
#pragma unroll
            for (int ix = 0; ix < 2; ++ix) {
                const int px  = pw * 2 + ix;
                const float w = wy * s_wx[qx][px];
                // ONE load: all 4 taps of this sample, 128 ch wave-wide
                const uint4 q = *(const uint4*)(fp + ybs + s_xb[qx][px]);
                const float2 f0 = __half22float2(u32_as_h2(q.x));
                const float2 f1 = __half22float2(u32_as_h2(q.y));
                const float2 f2 = __half22float2(u32_as_h2(q.z));
                const float2 f3 = __half22float2(u32_as_h2(q.w));
                acc[0] += w * f0.x;  acc[1] += w * f0.y;
                acc[2] += w * f1.x;  acc[3] += w * f1.y;
                acc[4] += w * f2.x;  acc[5] += w * f2.y;
                acc[6] += w * f3.x;  acc[7] += w * f3.y;
            }
        }
        // reduce the 4 quarters: x-taps (lane^16), then y-taps (lane^32)
#pragma unroll
        for (int j = 0; j < 8; ++j) {
            acc[j] += __shfl_xor(acc[j], 16);
            acc[j] += __shfl_xor(acc[j], 32);
        }
        // quarter 0 only: no 4-way same-address conflict, 1/4 the ds_writes
        if (lane < 16) {
#pragma unroll
            for (int j = 0; j < 8; ++j) {
                buf_f[(c8 + j) * NBIN + bin] = acc[j];
            }
        }
    }
    __syncthreads();

    // Drain: buf_f is this half's linear (128,7,7) fp32 order; region is
    // exactly 392 full 64B lines -> clean coalesced nontemporal float4 stores,
    // no conversion needed.
    nfloat4* ob = (nfloat4*)(out + (size_t)n * PER_ROI + cb * HALF_OUT);
    const nfloat4* bb = (const nfloat4*)buf_f;
    for (int i = tid; i < HALF_OUT / 4; i += 512) {
        __builtin_nontemporal_store(bb[i], ob + i);
    }
}

// ---------------------------------------------------------------------------
// Fallback (workspace too small): original-layout fp32, correct but slow.
// ---------------------------------------------------------------------------
__global__ __launch_bounds__(256) void roi_align_direct_k(const float* __restrict__ f,
                                                          const float* __restrict__ rois,
                                                          float* __restrict__ out) {
    const int n   = blockIdx.x;
    const int c   = threadIdx.x;

    __shared__ int   s_y0[14], s_y1[14], s_x0[14], s_x1[14];
    __shared__ float s_ly[14], s_lx[14], s_vy[14], s_vx[14];

    const float* r = rois + n * 5;
    const int   b   = (int)r[0];
    const float rx1 = r[1] * SCALEF, ry1 = r[2] * SCALEF;
    const float rx2 = r[3] * SCALEF, ry2 = r[4] * SCALEF;
    const float bw = fmaxf(rx2 - rx1, 1.0f) * (1.0f / OW);
    const float bh = fmaxf(ry2 - ry1, 1.0f) * (1.0f / OH);

    if (c < 14) {
        const float ys = ry1 + ((float)c + 0.5f) * (bh * 0.5f);
        s_vy[c] = (ys >= -1.0f && ys <= (float)HH) ? 1.0f : 0.0f;
        const float y = fminf(fmaxf(ys, 0.0f), (float)(HH - 1));
        const int y0  = (int)floorf(y);
        s_y0[c] = y0 * WW;
        s_y1[c] = min(y0 + 1, HH - 1) * WW;
        s_ly[c] = y - (float)y0;
    } else if (c >= 64 && c < 78) {
        const int j = c - 64;
        const float xs = rx1 + ((float)j + 0.5f) * (bw * 0.5f);
        s_vx[j] = (xs >= -1.0f && xs <= (float)WW) ? 1.0f : 0.0f;
        const float x = fminf(fmaxf(xs, 0.0f), (float)(WW - 1));
        const int x0  = (int)floorf(x);
        s_x0[j] = x0;
        s_x1[j] = min(x0 + 1, WW - 1);
        s_lx[j] = x - (float)x0;
    }
    __syncthreads();

    const float* fb = f + (size_t)(b * CCH + c) * HWN;
    for (int bin = 0; bin < NBIN; ++bin) {
        const int ph = bin / OW, pw = bin - ph * OW;
        float acc = 0.0f;
        for (int iy = 0; iy < 2; ++iy) {
            const int py = ph * 2 + iy;
            const float ly = s_ly[py], hy = 1.0f - ly;
            for (int ix = 0; ix < 2; ++ix) {
                const int px = pw * 2 + ix;
                const float lx = s_lx[px], hx = 1.0f - lx;
                const float m = s_vy[py] * s_vx[px] * 0.25f;
                acc += m * (hy * (hx * fb[s_y0[py] + s_x0[px]] + lx * fb[s_y0[py] + s_x1[px]]) +
                            ly * (hx * fb[s_y1[py] + s_x0[px]] + lx * fb[s_y1[py] + s_x1[px]]));
            }
        }
        out[(size_t)n * PER_ROI + c * NBIN + bin] = acc;
    }
}

extern "C" void kernel_launch(void* const* d_in, const int* in_sizes, int n_in,
                              void* d_out, int out_size, void* d_ws, size_t ws_size,
                              hipStream_t stream) {
    const float* feat = (const float*)d_in[0];
    const float* rois = (const float*)d_in[1];
    float* out = (float*)d_out;
    const int N = in_sizes[1] / 5;

    const size_t tensor_bytes = (size_t)BB * CCH * HWN * sizeof(unsigned short); // 68.8 MB
    const size_t need = tensor_bytes + (size_t)N * sizeof(int);
    if (ws_size >= need) {
        unsigned short* fcl = (unsigned short*)d_ws;
        int* perm = (int*)((char*)d_ws + tensor_bytes);   // tensor_bytes is 256-aligned
        transpose_f16_k<<<dim3(HWN / 64, CCH / 128, BB), dim3(16, 16), 0, stream>>>(
            feat, fcl, rois, N, perm);
        roi_align_f16_k<<<dim3(N, 2), 512, 0, stream>>>(fcl, rois, perm, out);
    } else {
        roi_align_direct_k<<<N, 256, 0, stream>>>(feat, rois, out);
    }
}